// Round 4
// baseline (489.214 us; speedup 1.0000x reference)
//
#include <hip/hip_runtime.h>

// CrossAttention: B=2, C=256, H=W=64 (N=4096), NH=4 heads of hd=64, G=32 groups.
// Pipeline (all bf16 MFMA internally, fp32 I/O):
//   wcvt:     weights fp32 -> bf16
//   gnorm:    GroupNorm(input)->nqT[b][n][c], GroupNorm(c)->nkvT (transposed bf16)
//   proj_all: QT[b][n][256] = (nqT . wq^T)/16 ; K half -> KVT[b][n][512]
//             (per-head slots 128h..128h+63); V half -> VT[b][h][d][n]
//   attn:     S^T = K Q^T (A=K rows, B=Q rows) so lane's column is a fixed query
//             q=lane&15; no online max (|s|<~4, exp safe); KEY TRICK: the 16x16 C/D
//             layout (col=lane&15,row=4g+r) EQUALS the 16x16x16 B-operand layout
//             (n=lane&15,k=4g+j), so each 16-kk half of S^T is a ready PV B-frag
//             after in-lane f32->bf16 pack. ZERO shfl, ZERO LDS, ZERO barriers.
//             O^T += V^T P^T via K=16 MFMAs. bh=blockIdx&7 pins (b,h) to one XCD L2.
//   outproj:  out[b][o][n] = wout . Ot^T + bias + input   (fp32 out)

typedef __attribute__((ext_vector_type(8))) short short8;   // 8 x bf16 bits
typedef __attribute__((ext_vector_type(4))) short s4;       // 4 x bf16 bits
typedef __attribute__((ext_vector_type(4))) float f32x4;
typedef __attribute__((ext_vector_type(2))) unsigned int uint2v;
typedef __attribute__((ext_vector_type(4))) unsigned int uint4v;

__device__ __forceinline__ unsigned short f2bf(float x) {
    unsigned int u = __builtin_bit_cast(unsigned int, x);
    u += 0x7FFFu + ((u >> 16) & 1u);   // round-to-nearest-even
    return (unsigned short)(u >> 16);
}

// pack two positive floats to bf16 pair (round-to-nearest, no tie fix — P>=0)
__device__ __forceinline__ unsigned int pk2(float a, float b) {
    unsigned int ua = __builtin_bit_cast(unsigned int, a) + 0x8000u;
    unsigned int ub = __builtin_bit_cast(unsigned int, b) + 0x8000u;
    return (ua >> 16) | (ub & 0xFFFF0000u);
}

__device__ __forceinline__ short8 ld8(const unsigned short* p) {
    return *reinterpret_cast<const short8*>(p);
}

#define MFMA(a, b, c) __builtin_amdgcn_mfma_f32_16x16x32_bf16((a), (b), (c), 0, 0, 0)

#if __has_builtin(__builtin_amdgcn_mfma_f32_16x16x16bf16_1k)
#define HAVE_MFMA16 1
#define MFMA16(a, b, c) __builtin_amdgcn_mfma_f32_16x16x16bf16_1k((a), (b), (c), 0, 0, 0)
#endif

// ---------------------------------------------------------------- weights cvt
__global__ __launch_bounds__(256) void wcvt(const float* __restrict__ wq,
                                            const float* __restrict__ wkv,
                                            const float* __restrict__ wo,
                                            unsigned short* __restrict__ dst) {
    int i = blockIdx.x * 256 + threadIdx.x;   // 262144 total
    float v;
    if (i < 65536)       v = wq[i];
    else if (i < 196608) v = wkv[i - 65536];
    else                 v = wo[i - 196608];
    dst[i] = f2bf(v);
}

// ---------------------------------------------------------------- group norm
// grid.x = 128: [tensor(2)][b(2)][group(32)]; writes transposed bf16 [b][n][256]
__global__ __launch_bounds__(256) void gnorm(const float* __restrict__ x0,
                                             const float* __restrict__ x1,
                                             unsigned short* __restrict__ d0,
                                             unsigned short* __restrict__ d1,
                                             const float* __restrict__ gamma,
                                             const float* __restrict__ beta) {
    int bid = blockIdx.x;
    const float* x = (bid & 64) ? x1 : x0;
    unsigned short* dst = (bid & 64) ? d1 : d0;
    int b = (bid >> 5) & 1, g = bid & 31;
    const float* base = x + (size_t)(b * 256 + g * 8) * 4096;  // 8 ch x 4096, contiguous
    int tid = threadIdx.x, lane = tid & 63, w = tid >> 6;

    float s = 0.f, s2 = 0.f;
    const float4* b4 = (const float4*)base;          // 8192 float4
    for (int i = tid; i < 8192; i += 256) {
        float4 v = b4[i];
        s  += v.x + v.y + v.z + v.w;
        s2 += v.x * v.x + v.y * v.y + v.z * v.z + v.w * v.w;
    }
    #pragma unroll
    for (int off = 32; off; off >>= 1) {
        s  += __shfl_down(s, off);
        s2 += __shfl_down(s2, off);
    }
    __shared__ float red[8];
    __shared__ float stat[2];
    if (lane == 0) { red[w] = s; red[4 + w] = s2; }
    __syncthreads();
    if (tid == 0) {
        float S = red[0] + red[1] + red[2] + red[3];
        float S2 = red[4] + red[5] + red[6] + red[7];
        float mean = S * (1.f / 32768.f);
        float var = S2 * (1.f / 32768.f) - mean * mean;
        stat[0] = mean;
        stat[1] = rsqrtf(var + 1e-5f);
    }
    __syncthreads();
    float mean = stat[0], inv = stat[1];

    float a[8], c0[8];
    #pragma unroll
    for (int cl = 0; cl < 8; cl++) {
        float gm = gamma[g * 8 + cl], bt = beta[g * 8 + cl];
        a[cl]  = gm * inv;
        c0[cl] = bt - mean * gm * inv;
    }
    for (int n = tid; n < 4096; n += 256) {
        unsigned short o[8];
        #pragma unroll
        for (int cl = 0; cl < 8; cl++) {
            float v = base[cl * 4096 + n];            // coalesced per cl
            o[cl] = f2bf(v * a[cl] + c0[cl]);
        }
        *(uint4*)&dst[((size_t)(b * 4096 + n)) * 256 + g * 8] = *(const uint4*)o;
    }
}

// ---------------------------------------------------------------- projections
// grid (32, 12, 2): y<4 -> Q chunk y ; y>=4 -> KV chunk (y-4). 128 n-rows/block.
__global__ __launch_bounds__(256) void proj_all(const unsigned short* __restrict__ nqT,
                                                const unsigned short* __restrict__ nkvT,
                                                const unsigned short* __restrict__ Wq,
                                                const unsigned short* __restrict__ Wkv,
                                                unsigned short* __restrict__ QT,
                                                unsigned short* __restrict__ KVT,
                                                unsigned short* __restrict__ VT) {
    int bb = blockIdx.z;
    int y = blockIdx.y;
    bool isQ = (y < 4);
    int n0 = blockIdx.x * 128;
    int o0 = (isQ ? y : (y - 4)) * 64;
    int w = threadIdx.x >> 6, lane = threadIdx.x & 63;
    int m16 = lane & 15, g = lane >> 4;
    const unsigned short* Xb = (isQ ? nqT : nkvT) + (size_t)bb * 4096 * 256;
    const unsigned short* W = isQ ? Wq : Wkv;
    f32x4 acc[2][4] = {};
    int rowA = n0 + w * 32 + m16;
    #pragma unroll
    for (int k0 = 0; k0 < 256; k0 += 32) {
        short8 a0 = ld8(Xb + (size_t)rowA * 256 + k0 + g * 8);
        short8 a1 = ld8(Xb + (size_t)(rowA + 16) * 256 + k0 + g * 8);
        #pragma unroll
        for (int ct = 0; ct < 4; ct++) {
            short8 bf = ld8(W + (size_t)(o0 + ct * 16 + m16) * 256 + k0 + g * 8);
            acc[0][ct] = MFMA(a0, bf, acc[0][ct]);
            acc[1][ct] = MFMA(a1, bf, acc[1][ct]);
        }
    }
    if (isQ) {
        unsigned short* Ob = QT + (size_t)bb * 4096 * 256;
        #pragma unroll
        for (int mt = 0; mt < 2; mt++)
            #pragma unroll
            for (int ct = 0; ct < 4; ct++)
                #pragma unroll
                for (int r = 0; r < 4; r++) {
                    int n = n0 + w * 32 + mt * 16 + g * 4 + r;
                    int o = o0 + ct * 16 + m16;
                    Ob[(size_t)n * 256 + o] = f2bf(acc[mt][ct][r] * 0.0625f);
                }
    } else {
        int h2 = o0 >> 7, isV = (o0 >> 6) & 1;   // block-uniform
        unsigned short* Kb = KVT + (size_t)bb * 4096 * 512;
        unsigned short* Vb = VT + ((size_t)(bb * 4 + h2)) * 64 * 4096;
        #pragma unroll
        for (int mt = 0; mt < 2; mt++)
            #pragma unroll
            for (int ct = 0; ct < 4; ct++)
                #pragma unroll
                for (int r = 0; r < 4; r++) {
                    int n = n0 + w * 32 + mt * 16 + g * 4 + r;
                    int o = o0 + ct * 16 + m16;
                    unsigned short v = f2bf(acc[mt][ct][r]);
                    if (isV) Vb[(size_t)(o & 63) * 4096 + n] = v;
                    else     Kb[(size_t)n * 512 + o] = v;
                }
    }
}

// ---------------------------------------------------------------- attention
// 512 blocks: bh = blockIdx&7 (XCD-pinned), qb = blockIdx>>3. 4 waves x 16 q.
__global__ __launch_bounds__(256) void attn(const unsigned short* __restrict__ QT,
                                            const unsigned short* __restrict__ KVT,
                                            const unsigned short* __restrict__ VT,
                                            unsigned short* __restrict__ OT) {
    int bh = blockIdx.x & 7;
    int qb = blockIdx.x >> 3;
    int bb = bh >> 2, h = bh & 3;
    int w = threadIdx.x >> 6, lane = threadIdx.x & 63;
    int m16 = lane & 15, g = lane >> 4;

    int q0 = qb * 64 + w * 16;
    const unsigned short* Qb = QT + (size_t)bb * 4096 * 256;
    const unsigned short* Kp = KVT + (size_t)bb * 4096 * 512 + h * 128;  // K rows, stride 512
    const unsigned short* Vp = VT + (size_t)bh * 64 * 4096;              // V^T rows, stride 4096

    // Q B-frags (scale prefolded): B[n=q][k=c]
    short8 bq0 = ld8(Qb + (size_t)(q0 + m16) * 256 + h * 64 + g * 8);
    short8 bq1 = ld8(Qb + (size_t)(q0 + m16) * 256 + h * 64 + 32 + g * 8);

    f32x4 acc[4] = {};      // O^T: row d = dt*16 + 4g+r, col q = q0+m16
    float l = 0.f;          // sum of this lane's P values (column q)

#ifndef HAVE_MFMA16
    int sl0 = m16 + ((g & 1) << 5);
    int sl1 = sl0 + 16;
    bool hiT = (g >= 2);
#endif

    for (int kt = 0; kt < 4096; kt += 32) {
        // S^T tiles: A = K rows kk, B = Q rows q
        const unsigned short* kr0 = Kp + (size_t)(kt + m16) * 512;
        const unsigned short* kr1 = kr0 + 16 * 512;
        short8 a00 = ld8(kr0 + g * 8);
        short8 a01 = ld8(kr0 + 32 + g * 8);
        short8 a10 = ld8(kr1 + g * 8);
        short8 a11 = ld8(kr1 + 32 + g * 8);
        f32x4 s0 = {}, s1 = {};
        s0 = MFMA(a00, bq0, s0);
        s0 = MFMA(a01, bq1, s0);
        s1 = MFMA(a10, bq0, s1);
        s1 = MFMA(a11, bq1, s1);

        // exp (no max subtraction: |s| <~ 4 by construction)
        #pragma unroll
        for (int r = 0; r < 4; r++) {
            s0[r] = __expf(s0[r]);
            s1[r] = __expf(s1[r]);
        }
        l += (s0[0] + s0[1]) + (s0[2] + s0[3]) + (s1[0] + s1[1]) + (s1[2] + s1[3]);

#ifdef HAVE_MFMA16
        // C layout of each 16-kk S^T half == B-operand layout of 16x16x16 MFMA.
        uint2v w0; w0.x = pk2(s0[0], s0[1]); w0.y = pk2(s0[2], s0[3]);
        uint2v w1; w1.x = pk2(s1[0], s1[1]); w1.y = pk2(s1[2], s1[3]);
        s4 pb0 = __builtin_bit_cast(s4, w0);
        s4 pb1 = __builtin_bit_cast(s4, w1);
        #pragma unroll
        for (int dt = 0; dt < 4; dt++) {
            const unsigned short* vr = Vp + (size_t)(dt * 16 + m16) * 4096 + kt;
            s4 va0 = *(const s4*)(vr + g * 4);
            s4 va1 = *(const s4*)(vr + 16 + g * 4);
            acc[dt] = MFMA16(va0, pb0, acc[dt]);
            acc[dt] = MFMA16(va1, pb1, acc[dt]);
        }
#else
        // fallback: shfl-regroup C-layout -> K=32 B-frag (R3 path)
        unsigned int t0u0 = pk2(s0[0], s0[1]);
        unsigned int t0u1 = pk2(s0[2], s0[3]);
        unsigned int t1u0 = pk2(s1[0], s1[1]);
        unsigned int t1u1 = pk2(s1[2], s1[3]);
        unsigned int a0t0 = __shfl(t0u0, sl0), a1t0 = __shfl(t0u1, sl0);
        unsigned int a0t1 = __shfl(t1u0, sl0), a1t1 = __shfl(t1u1, sl0);
        unsigned int b0t0 = __shfl(t0u0, sl1), b1t0 = __shfl(t0u1, sl1);
        unsigned int b0t1 = __shfl(t1u0, sl1), b1t1 = __shfl(t1u1, sl1);
        uint4v pw;
        pw.x = hiT ? a0t1 : a0t0;
        pw.y = hiT ? a1t1 : a1t0;
        pw.z = hiT ? b0t1 : b0t0;
        pw.w = hiT ? b1t1 : b1t0;
        short8 pb = __builtin_bit_cast(short8, pw);
        #pragma unroll
        for (int dt = 0; dt < 4; dt++) {
            short8 va = ld8(Vp + (size_t)(dt * 16 + m16) * 4096 + kt + g * 8);
            acc[dt] = MFMA(va, pb, acc[dt]);
        }
#endif
    }

    // combine l across the 4 g-replicas of column q
    l += __shfl_xor(l, 16);
    l += __shfl_xor(l, 32);
    float invl = 1.f / l;

    unsigned short* Ob = OT + (size_t)bb * 4096 * 256;
    size_t obase = (size_t)(q0 + m16) * 256 + h * 64 + g * 4;
    #pragma unroll
    for (int dt = 0; dt < 4; dt++) {
        unsigned short o4[4];
        #pragma unroll
        for (int r = 0; r < 4; r++) o4[r] = f2bf(acc[dt][r] * invl);
        *(uint2*)&Ob[obase + dt * 16] = *(const uint2*)o4;
    }
}

// ---------------------------------------------------------------- out proj
// out[b][o][n] = wout[o][:] . Ot[b][n][:] + bias[o] + input[b][o][n]
__global__ __launch_bounds__(256) void outproj(const unsigned short* __restrict__ Ot,
                                               const unsigned short* __restrict__ Wo,
                                               const float* __restrict__ bias,
                                               const float* __restrict__ resid,
                                               float* __restrict__ out) {
    int bb = blockIdx.z;
    int n0 = blockIdx.x * 128;
    int o0 = blockIdx.y * 64;
    int w = threadIdx.x >> 6, lane = threadIdx.x & 63;
    int m16 = lane & 15, g = lane >> 4;
    const unsigned short* Ob = Ot + (size_t)bb * 4096 * 256;
    int orow = o0 + w * 16 + m16;
    f32x4 acc[8] = {};
    #pragma unroll
    for (int k0 = 0; k0 < 256; k0 += 32) {
        short8 a = ld8(Wo + (size_t)orow * 256 + k0 + g * 8);
        #pragma unroll
        for (int ct = 0; ct < 8; ct++) {
            short8 bf = ld8(Ob + (size_t)(n0 + ct * 16 + m16) * 256 + k0 + g * 8);
            acc[ct] = MFMA(a, bf, acc[ct]);
        }
    }
    float biasr[4];
    #pragma unroll
    for (int r = 0; r < 4; r++) biasr[r] = bias[o0 + w * 16 + g * 4 + r];
    #pragma unroll
    for (int ct = 0; ct < 8; ct++)
        #pragma unroll
        for (int r = 0; r < 4; r++) {
            int o = o0 + w * 16 + g * 4 + r;
            int n = n0 + ct * 16 + m16;
            size_t idx = ((size_t)bb * 256 + o) * 4096 + n;
            out[idx] = acc[ct][r] + biasr[r] + resid[idx];
        }
}

// ---------------------------------------------------------------- launch
extern "C" void kernel_launch(void* const* d_in, const int* in_sizes, int n_in,
                              void* d_out, int out_size, void* d_ws, size_t ws_size,
                              hipStream_t stream) {
    const float* input  = (const float*)d_in[0];
    const float* cctx   = (const float*)d_in[1];
    const float* gn_w   = (const float*)d_in[2];
    const float* gn_b   = (const float*)d_in[3];
    const float* wq     = (const float*)d_in[4];
    const float* wkv    = (const float*)d_in[5];
    const float* wout_w = (const float*)d_in[6];
    const float* wout_b = (const float*)d_in[7];
    float* out = (float*)d_out;

    unsigned short* ws = (unsigned short*)d_ws;
    unsigned short* wq_bf   = ws;                   //  65536 ush
    unsigned short* wkv_bf  = ws + 65536;           // 131072
    unsigned short* wout_bf = ws + 196608;          //  65536
    unsigned short* nqT  = ws + 262144;             // 2*4096*256
    unsigned short* nkvT = nqT + 2097152;
    unsigned short* QT   = nkvT + 2097152;
    unsigned short* KVT  = QT + 2097152;            // 2*4096*512 (V slots unused)
    unsigned short* OtT  = KVT + 4194304;
    unsigned short* VT   = KVT + 2097152;           // alias dead V slots? NO — use own region
    // VT gets its own region after OtT to keep proj_all's K and V writes disjoint
    VT = OtT + 2097152;                             // 2*4*64*4096 = 2097152 ush; total ~29 MiB

    wcvt<<<1024, 256, 0, stream>>>(wq, wkv, wout_w, ws);
    gnorm<<<128, 256, 0, stream>>>(input, cctx, nqT, nkvT, gn_w, gn_b);
    proj_all<<<dim3(32, 12, 2), 256, 0, stream>>>(nqT, nkvT, wq_bf, wkv_bf, QT, KVT, VT);
    attn<<<512, 256, 0, stream>>>(QT, KVT, VT, OtT);
    outproj<<<dim3(32, 4, 2), 256, 0, stream>>>(OtT, wout_bf, wout_b, input, out);
}

// Round 5
// 384.185 us; speedup vs baseline: 1.2734x; 1.2734x over previous
//
#include <hip/hip_runtime.h>

// CrossAttention: B=2, C=256, H=W=64 (N=4096), NH=4 heads of hd=64, G=32 groups.
// Pipeline (all bf16 MFMA internally, fp32 I/O):
//   wcvt:     weights fp32 -> bf16
//   gnorm:    GroupNorm(input)->nqT[b][n][c], GroupNorm(c)->nkvT (transposed bf16)
//   proj_all: QT[b][n][256] = (nqT . wq^T)/16 ; K half -> KVT[b][n][512]
//             (per-head slots 128h..128h+63); V half -> VT[b][h][d][n'] where n' is
//             a 4-element interleave perm within each 32-kk block so attn can load
//             both K=16 PV A-frags with ONE 16B load.
//   attn:     1024-thr blocks (16 waves = 4 q-tiles x 4 kk-quarters) -> 32 waves/CU.
//             S^T = K Q^T; no online max (|s|<~4); 16x16 C/D layout == 16x16x16
//             B-operand layout, so S^T halves feed PV directly (verified R4).
//             Quarter partials combined via LDS at the end (exp is linear in
//             partials since no max rescale). bh=blockIdx&7 pins (b,h) to one XCD.
//   outproj:  out[b][o][n] = wout . Ot^T + bias + input   (fp32 out)

typedef __attribute__((ext_vector_type(8))) short short8;   // 8 x bf16 bits
typedef __attribute__((ext_vector_type(4))) short s4;       // 4 x bf16 bits
typedef __attribute__((ext_vector_type(4))) float f32x4;
typedef __attribute__((ext_vector_type(2))) unsigned int uint2v;

__device__ __forceinline__ unsigned short f2bf(float x) {
    unsigned int u = __builtin_bit_cast(unsigned int, x);
    u += 0x7FFFu + ((u >> 16) & 1u);   // round-to-nearest-even
    return (unsigned short)(u >> 16);
}

// pack two positive floats to bf16 pair (round-to-nearest, no tie fix — P>=0)
__device__ __forceinline__ unsigned int pk2(float a, float b) {
    unsigned int ua = __builtin_bit_cast(unsigned int, a) + 0x8000u;
    unsigned int ub = __builtin_bit_cast(unsigned int, b) + 0x8000u;
    return (ua >> 16) | (ub & 0xFFFF0000u);
}

__device__ __forceinline__ short8 ld8(const unsigned short* p) {
    return *reinterpret_cast<const short8*>(p);
}

#define MFMA(a, b, c) __builtin_amdgcn_mfma_f32_16x16x32_bf16((a), (b), (c), 0, 0, 0)
#define MFMA16(a, b, c) __builtin_amdgcn_mfma_f32_16x16x16bf16_1k((a), (b), (c), 0, 0, 0)

// ---------------------------------------------------------------- weights cvt
__global__ __launch_bounds__(256) void wcvt(const float* __restrict__ wq,
                                            const float* __restrict__ wkv,
                                            const float* __restrict__ wo,
                                            unsigned short* __restrict__ dst) {
    int i = blockIdx.x * 256 + threadIdx.x;   // 262144 total
    float v;
    if (i < 65536)       v = wq[i];
    else if (i < 196608) v = wkv[i - 65536];
    else                 v = wo[i - 196608];
    dst[i] = f2bf(v);
}

// ---------------------------------------------------------------- group norm
// grid.x = 128: [tensor(2)][b(2)][group(32)]; writes transposed bf16 [b][n][256]
__global__ __launch_bounds__(256) void gnorm(const float* __restrict__ x0,
                                             const float* __restrict__ x1,
                                             unsigned short* __restrict__ d0,
                                             unsigned short* __restrict__ d1,
                                             const float* __restrict__ gamma,
                                             const float* __restrict__ beta) {
    int bid = blockIdx.x;
    const float* x = (bid & 64) ? x1 : x0;
    unsigned short* dst = (bid & 64) ? d1 : d0;
    int b = (bid >> 5) & 1, g = bid & 31;
    const float* base = x + (size_t)(b * 256 + g * 8) * 4096;  // 8 ch x 4096, contiguous
    int tid = threadIdx.x, lane = tid & 63, w = tid >> 6;

    float s = 0.f, s2 = 0.f;
    const float4* b4 = (const float4*)base;          // 8192 float4
    for (int i = tid; i < 8192; i += 256) {
        float4 v = b4[i];
        s  += v.x + v.y + v.z + v.w;
        s2 += v.x * v.x + v.y * v.y + v.z * v.z + v.w * v.w;
    }
    #pragma unroll
    for (int off = 32; off; off >>= 1) {
        s  += __shfl_down(s, off);
        s2 += __shfl_down(s2, off);
    }
    __shared__ float red[8];
    __shared__ float stat[2];
    if (lane == 0) { red[w] = s; red[4 + w] = s2; }
    __syncthreads();
    if (tid == 0) {
        float S = red[0] + red[1] + red[2] + red[3];
        float S2 = red[4] + red[5] + red[6] + red[7];
        float mean = S * (1.f / 32768.f);
        float var = S2 * (1.f / 32768.f) - mean * mean;
        stat[0] = mean;
        stat[1] = rsqrtf(var + 1e-5f);
    }
    __syncthreads();
    float mean = stat[0], inv = stat[1];

    float a[8], c0[8];
    #pragma unroll
    for (int cl = 0; cl < 8; cl++) {
        float gm = gamma[g * 8 + cl], bt = beta[g * 8 + cl];
        a[cl]  = gm * inv;
        c0[cl] = bt - mean * gm * inv;
    }
    for (int n = tid; n < 4096; n += 256) {
        unsigned short o[8];
        #pragma unroll
        for (int cl = 0; cl < 8; cl++) {
            float v = base[cl * 4096 + n];            // coalesced per cl
            o[cl] = f2bf(v * a[cl] + c0[cl]);
        }
        *(uint4*)&dst[((size_t)(b * 4096 + n)) * 256 + g * 8] = *(const uint4*)o;
    }
}

// ---------------------------------------------------------------- projections
// grid (32, 12, 2): y<4 -> Q chunk y ; y>=4 -> KV chunk (y-4). 128 n-rows/block.
__global__ __launch_bounds__(256) void proj_all(const unsigned short* __restrict__ nqT,
                                                const unsigned short* __restrict__ nkvT,
                                                const unsigned short* __restrict__ Wq,
                                                const unsigned short* __restrict__ Wkv,
                                                unsigned short* __restrict__ QT,
                                                unsigned short* __restrict__ KVT,
                                                unsigned short* __restrict__ VT) {
    int bb = blockIdx.z;
    int y = blockIdx.y;
    bool isQ = (y < 4);
    int n0 = blockIdx.x * 128;
    int o0 = (isQ ? y : (y - 4)) * 64;
    int w = threadIdx.x >> 6, lane = threadIdx.x & 63;
    int m16 = lane & 15, g = lane >> 4;
    const unsigned short* Xb = (isQ ? nqT : nkvT) + (size_t)bb * 4096 * 256;
    const unsigned short* W = isQ ? Wq : Wkv;
    f32x4 acc[2][4] = {};
    int rowA = n0 + w * 32 + m16;
    #pragma unroll
    for (int k0 = 0; k0 < 256; k0 += 32) {
        short8 a0 = ld8(Xb + (size_t)rowA * 256 + k0 + g * 8);
        short8 a1 = ld8(Xb + (size_t)(rowA + 16) * 256 + k0 + g * 8);
        #pragma unroll
        for (int ct = 0; ct < 4; ct++) {
            short8 bf = ld8(W + (size_t)(o0 + ct * 16 + m16) * 256 + k0 + g * 8);
            acc[0][ct] = MFMA(a0, bf, acc[0][ct]);
            acc[1][ct] = MFMA(a1, bf, acc[1][ct]);
        }
    }
    if (isQ) {
        unsigned short* Ob = QT + (size_t)bb * 4096 * 256;
        #pragma unroll
        for (int mt = 0; mt < 2; mt++)
            #pragma unroll
            for (int ct = 0; ct < 4; ct++)
                #pragma unroll
                for (int r = 0; r < 4; r++) {
                    int n = n0 + w * 32 + mt * 16 + g * 4 + r;
                    int o = o0 + ct * 16 + m16;
                    Ob[(size_t)n * 256 + o] = f2bf(acc[mt][ct][r] * 0.0625f);
                }
    } else {
        int h2 = o0 >> 7, isV = (o0 >> 6) & 1;   // block-uniform
        unsigned short* Kb = KVT + (size_t)bb * 4096 * 512;
        unsigned short* Vb = VT + ((size_t)(bb * 4 + h2)) * 64 * 4096;
        #pragma unroll
        for (int mt = 0; mt < 2; mt++)
            #pragma unroll
            for (int ct = 0; ct < 4; ct++)
                #pragma unroll
                for (int r = 0; r < 4; r++) {
                    int n = n0 + w * 32 + mt * 16 + g * 4 + r;
                    int o = o0 + ct * 16 + m16;
                    unsigned short v = f2bf(acc[mt][ct][r]);
                    if (isV) {
                        // perm within 32-block: c=mt*16+g*4+r -> 8g+4mt+r so attn's
                        // single 16B load = {kk 4g..4g+3} ++ {kk 16+4g..16+4g+3}
                        int np = n0 + w * 32 + g * 8 + mt * 4 + r;
                        Vb[(size_t)(o & 63) * 4096 + np] = v;
                    } else {
                        Kb[(size_t)n * 512 + o] = v;
                    }
                }
    }
}

// ---------------------------------------------------------------- attention
// 512 blocks x 1024 thr: bh = blockIdx&7 (XCD-pinned), qb = blockIdx>>3 (64 q).
// 16 waves: t = w&3 (q-tile), quarter = w>>2 (kk range). LDS combine at end.
__global__ __launch_bounds__(1024, 8) void attn(const unsigned short* __restrict__ QT,
                                                const unsigned short* __restrict__ KVT,
                                                const unsigned short* __restrict__ VT,
                                                unsigned short* __restrict__ OT) {
    __shared__ float Of[64 * 65];   // [d][q] partial O^T, stride 65 vs conflicts
    __shared__ float lf[64];        // [q] partial l
    int bh = blockIdx.x & 7;
    int qb = blockIdx.x >> 3;
    int bb = bh >> 2, h = bh & 3;
    int w = threadIdx.x >> 6, lane = threadIdx.x & 63;
    int t = w & 3, quarter = w >> 2;
    int m16 = lane & 15, g = lane >> 4;

    int q0 = qb * 64 + t * 16;
    const unsigned short* Qb = QT + (size_t)bb * 4096 * 256;
    const unsigned short* Kp = KVT + (size_t)bb * 4096 * 512 + h * 128;  // K rows, stride 512
    const unsigned short* Vp = VT + (size_t)bh * 64 * 4096;              // V^T rows (permuted)

    // Q B-frags (scale prefolded): B[n=q][k=c]
    short8 bq0 = ld8(Qb + (size_t)(q0 + m16) * 256 + h * 64 + g * 8);
    short8 bq1 = ld8(Qb + (size_t)(q0 + m16) * 256 + h * 64 + 32 + g * 8);

    f32x4 acc[4] = {};      // O^T partial: row d = dt*16 + 4g+r, col q = q0+m16
    float l = 0.f;

    int kbeg = quarter * 1024;
    for (int kt = kbeg; kt < kbeg + 1024; kt += 32) {
        // S^T tiles: A = K rows kk, B = Q rows q
        const unsigned short* kr0 = Kp + (size_t)(kt + m16) * 512;
        const unsigned short* kr1 = kr0 + 16 * 512;
        short8 a00 = ld8(kr0 + g * 8);
        short8 a01 = ld8(kr0 + 32 + g * 8);
        short8 a10 = ld8(kr1 + g * 8);
        short8 a11 = ld8(kr1 + 32 + g * 8);
        f32x4 s0 = {}, s1 = {};
        s0 = MFMA(a00, bq0, s0);
        s0 = MFMA(a01, bq1, s0);
        s1 = MFMA(a10, bq0, s1);
        s1 = MFMA(a11, bq1, s1);

        // exp (no max subtraction: |s| <~ 4 by construction)
        #pragma unroll
        for (int r = 0; r < 4; r++) {
            s0[r] = __expf(s0[r]);
            s1[r] = __expf(s1[r]);
        }
        l += (s0[0] + s0[1]) + (s0[2] + s0[3]) + (s1[0] + s1[1]) + (s1[2] + s1[3]);

        // C layout of each 16-kk S^T half == B-operand layout of 16x16x16 MFMA (R4-verified)
        uint2v w0; w0.x = pk2(s0[0], s0[1]); w0.y = pk2(s0[2], s0[3]);
        uint2v w1; w1.x = pk2(s1[0], s1[1]); w1.y = pk2(s1[2], s1[3]);
        s4 pb0 = __builtin_bit_cast(s4, w0);
        s4 pb1 = __builtin_bit_cast(s4, w1);
        #pragma unroll
        for (int dt = 0; dt < 4; dt++) {
            short8 va = ld8(Vp + (size_t)(dt * 16 + m16) * 4096 + kt + g * 8);  // permuted
            s4 va0 = __builtin_shufflevector(va, va, 0, 1, 2, 3);
            s4 va1 = __builtin_shufflevector(va, va, 4, 5, 6, 7);
            acc[dt] = MFMA16(va0, pb0, acc[dt]);
            acc[dt] = MFMA16(va1, pb1, acc[dt]);
        }
    }

    // combine l across the 4 g-replicas of column q (within wave)
    l += __shfl_xor(l, 16);
    l += __shfl_xor(l, 32);

    // cross-quarter combine via LDS, 4 phases
    #pragma unroll
    for (int p = 0; p < 4; p++) {
        if (quarter == p) {
            #pragma unroll
            for (int dt = 0; dt < 4; dt++)
                #pragma unroll
                for (int r = 0; r < 4; r++) {
                    int idx = (dt * 16 + g * 4 + r) * 65 + t * 16 + m16;
                    if (p == 0) Of[idx] = acc[dt][r];
                    else        Of[idx] += acc[dt][r];
                }
            if (lane < 16) {
                if (p == 0) lf[t * 16 + m16] = l;
                else        lf[t * 16 + m16] += l;
            }
        }
        __syncthreads();
    }

    // all 1024 threads: normalize + write Ot[b][n][256]
    int tid = threadIdx.x;
    int ql = tid >> 4, d4 = (tid & 15) * 4;
    float invl = 1.f / lf[ql];
    unsigned short o4[4];
    #pragma unroll
    for (int j = 0; j < 4; j++) o4[j] = f2bf(Of[(d4 + j) * 65 + ql] * invl);
    unsigned short* Ob = OT + (size_t)bb * 4096 * 256;
    *(uint2*)&Ob[(size_t)(qb * 64 + ql) * 256 + h * 64 + d4] = *(const uint2*)o4;
}

// ---------------------------------------------------------------- out proj
// out[b][o][n] = wout[o][:] . Ot[b][n][:] + bias[o] + input[b][o][n]
__global__ __launch_bounds__(256) void outproj(const unsigned short* __restrict__ Ot,
                                               const unsigned short* __restrict__ Wo,
                                               const float* __restrict__ bias,
                                               const float* __restrict__ resid,
                                               float* __restrict__ out) {
    int bb = blockIdx.z;
    int n0 = blockIdx.x * 128;
    int o0 = blockIdx.y * 64;
    int w = threadIdx.x >> 6, lane = threadIdx.x & 63;
    int m16 = lane & 15, g = lane >> 4;
    const unsigned short* Ob = Ot + (size_t)bb * 4096 * 256;
    int orow = o0 + w * 16 + m16;
    f32x4 acc[8] = {};
    #pragma unroll
    for (int k0 = 0; k0 < 256; k0 += 32) {
        short8 a = ld8(Wo + (size_t)orow * 256 + k0 + g * 8);
        #pragma unroll
        for (int ct = 0; ct < 8; ct++) {
            short8 bf = ld8(Ob + (size_t)(n0 + ct * 16 + m16) * 256 + k0 + g * 8);
            acc[ct] = MFMA(a, bf, acc[ct]);
        }
    }
    float biasr[4];
    #pragma unroll
    for (int r = 0; r < 4; r++) biasr[r] = bias[o0 + w * 16 + g * 4 + r];
    #pragma unroll
    for (int ct = 0; ct < 8; ct++)
        #pragma unroll
        for (int r = 0; r < 4; r++) {
            int o = o0 + w * 16 + g * 4 + r;
            int n = n0 + ct * 16 + m16;
            size_t idx = ((size_t)bb * 256 + o) * 4096 + n;
            out[idx] = acc[ct][r] + biasr[r] + resid[idx];
        }
}

// ---------------------------------------------------------------- launch
extern "C" void kernel_launch(void* const* d_in, const int* in_sizes, int n_in,
                              void* d_out, int out_size, void* d_ws, size_t ws_size,
                              hipStream_t stream) {
    const float* input  = (const float*)d_in[0];
    const float* cctx   = (const float*)d_in[1];
    const float* gn_w   = (const float*)d_in[2];
    const float* gn_b   = (const float*)d_in[3];
    const float* wq     = (const float*)d_in[4];
    const float* wkv    = (const float*)d_in[5];
    const float* wout_w = (const float*)d_in[6];
    const float* wout_b = (const float*)d_in[7];
    float* out = (float*)d_out;

    unsigned short* ws = (unsigned short*)d_ws;
    unsigned short* wq_bf   = ws;                   //  65536 ush
    unsigned short* wkv_bf  = ws + 65536;           // 131072
    unsigned short* wout_bf = ws + 196608;          //  65536
    unsigned short* nqT  = ws + 262144;             // 2*4096*256
    unsigned short* nkvT = nqT + 2097152;
    unsigned short* QT   = nkvT + 2097152;
    unsigned short* KVT  = QT + 2097152;            // 2*4096*512 (V slots unused)
    unsigned short* OtT  = KVT + 4194304;
    unsigned short* VT   = OtT + 2097152;           // 2*4*64*4096; total ~29.9 MiB

    wcvt<<<1024, 256, 0, stream>>>(wq, wkv, wout_w, ws);
    gnorm<<<128, 256, 0, stream>>>(input, cctx, nqT, nkvT, gn_w, gn_b);
    proj_all<<<dim3(32, 12, 2), 256, 0, stream>>>(nqT, nkvT, wq_bf, wkv_bf, QT, KVT, VT);
    attn<<<512, 1024, 0, stream>>>(QT, KVT, VT, OtT);
    outproj<<<dim3(32, 4, 2), 256, 0, stream>>>(OtT, wout_bf, wout_b, input, out);
}

// Round 6
// 200.235 us; speedup vs baseline: 2.4432x; 1.9187x over previous
//
#include <hip/hip_runtime.h>

// CrossAttention: B=2, C=256, H=W=64 (N=4096), NH=4 heads of hd=64, G=32 groups.
//   wcvt:     weights fp32 -> bf16
//   gnorm:    GroupNorm -> nqT/nkvT [b][n][256] bf16
//   proj_all: Q -> QT[b][n][256] (1/16 prefolded). K -> KF, V -> VF: FRAG-ORDERED
//             layouts (1KB per MFMA fragment, lane-major) so attn stages LDS with a
//             linear 16B/thread copy and reads frags via conflict-free ds_read_b128.
//             KF[bh][T16][cb][lane][8]: lane=m16+16g holds K[T16*16+m16][cb*32+g*8+e]
//             VF[bh][T32][dt][lane][8]: lane=m16+16g holds V^T[dt*16+m16][T32*32+vperm]
//             vperm(g,j) = j<4 ? 4g+j : 16+4g+(j-4)  (pairs two K=16 PV A-frags/16B)
//   attn:     512 thr = 8 waves = 4 q-tiles x 2 key-halves; grid 64qb x 8bh = 512
//             (2 blocks/CU). Double-buffered LDS K/V tiles (64KB). S^T = K Q^T;
//             no online max (|s|<~4); S^T C-tile == MFMA16 B-frag (R4/R5-verified);
//             2-half combine via LDS at end. bh=blk&7 pins (b,h) to one XCD L2.
//   outproj:  out = wout . Ot^T + bias + input (fp32)

typedef __attribute__((ext_vector_type(8))) short short8;   // 8 x bf16 bits
typedef __attribute__((ext_vector_type(4))) short s4;       // 4 x bf16 bits
typedef __attribute__((ext_vector_type(4))) float f32x4;
typedef __attribute__((ext_vector_type(2))) unsigned int uint2v;

__device__ __forceinline__ unsigned short f2bf(float x) {
    unsigned int u = __builtin_bit_cast(unsigned int, x);
    u += 0x7FFFu + ((u >> 16) & 1u);   // round-to-nearest-even
    return (unsigned short)(u >> 16);
}

__device__ __forceinline__ unsigned int pk2(float a, float b) {
    unsigned int ua = __builtin_bit_cast(unsigned int, a) + 0x8000u;
    unsigned int ub = __builtin_bit_cast(unsigned int, b) + 0x8000u;
    return (ua >> 16) | (ub & 0xFFFF0000u);
}

__device__ __forceinline__ short8 ld8(const unsigned short* p) {
    return *reinterpret_cast<const short8*>(p);
}

#define MFMA(a, b, c) __builtin_amdgcn_mfma_f32_16x16x32_bf16((a), (b), (c), 0, 0, 0)
#define MFMA16(a, b, c) __builtin_amdgcn_mfma_f32_16x16x16bf16_1k((a), (b), (c), 0, 0, 0)

// ---------------------------------------------------------------- weights cvt
__global__ __launch_bounds__(256) void wcvt(const float* __restrict__ wq,
                                            const float* __restrict__ wkv,
                                            const float* __restrict__ wo,
                                            unsigned short* __restrict__ dst) {
    int i = blockIdx.x * 256 + threadIdx.x;   // 262144 total
    float v;
    if (i < 65536)       v = wq[i];
    else if (i < 196608) v = wkv[i - 65536];
    else                 v = wo[i - 196608];
    dst[i] = f2bf(v);
}

// ---------------------------------------------------------------- group norm
__global__ __launch_bounds__(256) void gnorm(const float* __restrict__ x0,
                                             const float* __restrict__ x1,
                                             unsigned short* __restrict__ d0,
                                             unsigned short* __restrict__ d1,
                                             const float* __restrict__ gamma,
                                             const float* __restrict__ beta) {
    int bid = blockIdx.x;
    const float* x = (bid & 64) ? x1 : x0;
    unsigned short* dst = (bid & 64) ? d1 : d0;
    int b = (bid >> 5) & 1, g = bid & 31;
    const float* base = x + (size_t)(b * 256 + g * 8) * 4096;
    int tid = threadIdx.x, lane = tid & 63, w = tid >> 6;

    float s = 0.f, s2 = 0.f;
    const float4* b4 = (const float4*)base;
    for (int i = tid; i < 8192; i += 256) {
        float4 v = b4[i];
        s  += v.x + v.y + v.z + v.w;
        s2 += v.x * v.x + v.y * v.y + v.z * v.z + v.w * v.w;
    }
    #pragma unroll
    for (int off = 32; off; off >>= 1) {
        s  += __shfl_down(s, off);
        s2 += __shfl_down(s2, off);
    }
    __shared__ float red[8];
    __shared__ float stat[2];
    if (lane == 0) { red[w] = s; red[4 + w] = s2; }
    __syncthreads();
    if (tid == 0) {
        float S = red[0] + red[1] + red[2] + red[3];
        float S2 = red[4] + red[5] + red[6] + red[7];
        float mean = S * (1.f / 32768.f);
        float var = S2 * (1.f / 32768.f) - mean * mean;
        stat[0] = mean;
        stat[1] = rsqrtf(var + 1e-5f);
    }
    __syncthreads();
    float mean = stat[0], inv = stat[1];

    float a[8], c0[8];
    #pragma unroll
    for (int cl = 0; cl < 8; cl++) {
        float gm = gamma[g * 8 + cl], bt = beta[g * 8 + cl];
        a[cl]  = gm * inv;
        c0[cl] = bt - mean * gm * inv;
    }
    for (int n = tid; n < 4096; n += 256) {
        unsigned short o[8];
        #pragma unroll
        for (int cl = 0; cl < 8; cl++) {
            float v = base[cl * 4096 + n];
            o[cl] = f2bf(v * a[cl] + c0[cl]);
        }
        *(uint4*)&dst[((size_t)(b * 4096 + n)) * 256 + g * 8] = *(const uint4*)o;
    }
}

// ---------------------------------------------------------------- projections
// grid (32, 12, 2): y<4 -> Q chunk y ; y>=4 -> KV chunk (y-4). 128 n-rows/block.
__global__ __launch_bounds__(256) void proj_all(const unsigned short* __restrict__ nqT,
                                                const unsigned short* __restrict__ nkvT,
                                                const unsigned short* __restrict__ Wq,
                                                const unsigned short* __restrict__ Wkv,
                                                unsigned short* __restrict__ QT,
                                                unsigned short* __restrict__ KF,
                                                unsigned short* __restrict__ VF) {
    int bb = blockIdx.z;
    int y = blockIdx.y;
    bool isQ = (y < 4);
    int n0 = blockIdx.x * 128;
    int o0 = (isQ ? y : (y - 4)) * 64;
    int w = threadIdx.x >> 6, lane = threadIdx.x & 63;
    int m16 = lane & 15, g = lane >> 4;
    const unsigned short* Xb = (isQ ? nqT : nkvT) + (size_t)bb * 4096 * 256;
    const unsigned short* W = isQ ? Wq : Wkv;
    f32x4 acc[2][4] = {};
    int rowA = n0 + w * 32 + m16;
    #pragma unroll
    for (int k0 = 0; k0 < 256; k0 += 32) {
        short8 a0 = ld8(Xb + (size_t)rowA * 256 + k0 + g * 8);
        short8 a1 = ld8(Xb + (size_t)(rowA + 16) * 256 + k0 + g * 8);
        #pragma unroll
        for (int ct = 0; ct < 4; ct++) {
            short8 bf = ld8(W + (size_t)(o0 + ct * 16 + m16) * 256 + k0 + g * 8);
            acc[0][ct] = MFMA(a0, bf, acc[0][ct]);
            acc[1][ct] = MFMA(a1, bf, acc[1][ct]);
        }
    }
    if (isQ) {
        unsigned short* Ob = QT + (size_t)bb * 4096 * 256;
        #pragma unroll
        for (int mt = 0; mt < 2; mt++)
            #pragma unroll
            for (int ct = 0; ct < 4; ct++)
                #pragma unroll
                for (int r = 0; r < 4; r++) {
                    int n = n0 + w * 32 + mt * 16 + g * 4 + r;
                    int o = o0 + ct * 16 + m16;
                    Ob[(size_t)n * 256 + o] = f2bf(acc[mt][ct][r] * 0.0625f);
                }
    } else {
        int h2 = o0 >> 7, isV = (o0 >> 6) & 1;
        int bh = bb * 4 + h2;
        unsigned short* base = (isV ? VF : KF) + (size_t)bh * 262144;
        #pragma unroll
        for (int mt = 0; mt < 2; mt++)
            #pragma unroll
            for (int ct = 0; ct < 4; ct++)
                #pragma unroll
                for (int r = 0; r < 4; r++) {
                    int n = n0 + w * 32 + mt * 16 + g * 4 + r;   // kk
                    int c = ct * 16 + m16;                        // head channel
                    unsigned short v = f2bf(acc[mt][ct][r]);
                    size_t off;
                    if (isV) {
                        int T32 = n >> 5, kk5 = n & 31;
                        int gg = (kk5 & 15) >> 2;
                        int j = (kk5 & 3) + ((kk5 >> 4) << 2);
                        off = (((size_t)(T32 * 4 + ct)) * 64 + ((c & 15) + 16 * gg)) * 8 + j;
                    } else {
                        int T16 = n >> 4;
                        int cb = c >> 5, gg = (c >> 3) & 3, e = c & 7;
                        off = (((size_t)(T16 * 2 + cb)) * 64 + ((n & 15) + 16 * gg)) * 8 + e;
                    }
                    base[off] = v;
                }
    }
}

// ---------------------------------------------------------------- attention
// 512 blocks x 512 thr. bh=blk&7, qb=blk>>3 (64 q). 8 waves: wq=w&3, half hh=w>>2.
__global__ __launch_bounds__(512, 2) void attn(const unsigned short* __restrict__ QT,
                                               const unsigned short* __restrict__ KF,
                                               const unsigned short* __restrict__ VF,
                                               unsigned short* __restrict__ OT) {
    __shared__ unsigned short sm[32768];   // 64KB: K dbufs [0,16384), V dbufs [16384,32768)
    int bh = blockIdx.x & 7;
    int qb = blockIdx.x >> 3;
    int bb = bh >> 2, h = bh & 3;
    int tid = threadIdx.x;
    int w = tid >> 6, lane = tid & 63;
    int wq = w & 3, hh = w >> 2;
    int m16 = lane & 15, g = lane >> 4;
    int tloc = tid & 255;

    const unsigned short* KFb = KF + (size_t)bh * 262144;
    const unsigned short* VFb = VF + (size_t)bh * 262144;
    const unsigned short* Qb = QT + (size_t)bb * 4096 * 256;

    int q0 = qb * 64 + wq * 16;
    short8 bq0 = ld8(Qb + (size_t)(q0 + m16) * 256 + h * 64 + g * 8);
    short8 bq1 = ld8(Qb + (size_t)(q0 + m16) * 256 + h * 64 + 32 + g * 8);

    f32x4 acc[4] = {};
    float l = 0.f;

    // prologue: stage tile 0 of my half into dbuf 0
    {
        const uint4* ks = (const uint4*)(KFb + (size_t)(hh * 128) * 1024) + tloc;
        const uint4* vs = (const uint4*)(VFb + (size_t)(hh * 64) * 2048) + tloc;
        uint4 k0 = ks[0], k1 = ks[256], v0 = vs[0], v1 = vs[256];
        uint4* kd = (uint4*)(sm + (hh * 2) * 4096) + tloc;
        uint4* vd = (uint4*)(sm + 16384 + (hh * 2) * 4096) + tloc;
        kd[0] = k0; kd[256] = k1; vd[0] = v0; vd[256] = v1;
    }
    __syncthreads();

    for (int it = 0; it < 32; ++it) {
        int p = it & 1;
        bool pf = (it + 1 < 32);
        uint4 kp0, kp1, vp0, vp1;
        if (pf) {   // prefetch next tile into regs
            const uint4* ks = (const uint4*)(KFb + (size_t)(hh * 128 + (it + 1) * 4) * 1024) + tloc;
            const uint4* vs = (const uint4*)(VFb + (size_t)(hh * 64 + (it + 1) * 2) * 2048) + tloc;
            kp0 = ks[0]; kp1 = ks[256]; vp0 = vs[0]; vp1 = vs[256];
        }

        const unsigned short* Kbuf = sm + (hh * 2 + p) * 4096;
        const unsigned short* Vbuf = sm + 16384 + (hh * 2 + p) * 4096;

        s4 pb[4];
        #pragma unroll
        for (int t16 = 0; t16 < 4; t16++) {
            short8 a0 = ld8(Kbuf + (t16 * 2 + 0) * 512 + lane * 8);
            short8 a1 = ld8(Kbuf + (t16 * 2 + 1) * 512 + lane * 8);
            f32x4 st = {};
            st = MFMA(a0, bq0, st);
            st = MFMA(a1, bq1, st);
            #pragma unroll
            for (int r = 0; r < 4; r++) st[r] = __expf(st[r]);
            l += (st[0] + st[1]) + (st[2] + st[3]);
            uint2v wv; wv.x = pk2(st[0], st[1]); wv.y = pk2(st[2], st[3]);
            pb[t16] = __builtin_bit_cast(s4, wv);
        }
        #pragma unroll
        for (int T32 = 0; T32 < 2; T32++)
            #pragma unroll
            for (int dt = 0; dt < 4; dt++) {
                short8 va = ld8(Vbuf + (T32 * 4 + dt) * 512 + lane * 8);
                s4 va0 = __builtin_shufflevector(va, va, 0, 1, 2, 3);
                s4 va1 = __builtin_shufflevector(va, va, 4, 5, 6, 7);
                acc[dt] = MFMA16(va0, pb[T32 * 2], acc[dt]);
                acc[dt] = MFMA16(va1, pb[T32 * 2 + 1], acc[dt]);
            }

        if (pf) {   // write prefetched tile into the other dbuf
            uint4* kd = (uint4*)(sm + (hh * 2 + (p ^ 1)) * 4096) + tloc;
            uint4* vd = (uint4*)(sm + 16384 + (hh * 2 + (p ^ 1)) * 4096) + tloc;
            kd[0] = kp0; kd[256] = kp1; vd[0] = vp0; vd[256] = vp1;
        }
        __syncthreads();
    }

    // l: combine g-replicas of column q within wave
    l += __shfl_xor(l, 16);
    l += __shfl_xor(l, 32);

    // cross-half combine via LDS (staging bufs dead after last barrier)
    float* Cf = (float*)sm;            // [wq][d 64][q 16] = 4096 floats
    float* Lf = (float*)sm + 4096;     // [wq][16]
    if (hh == 1) {
        #pragma unroll
        for (int dt = 0; dt < 4; dt++)
            #pragma unroll
            for (int r = 0; r < 4; r++)
                Cf[wq * 1024 + (dt * 16 + g * 4 + r) * 16 + m16] = acc[dt][r];
        if (lane < 16) Lf[wq * 16 + m16] = l;
    }
    __syncthreads();
    if (hh == 0) {
        #pragma unroll
        for (int dt = 0; dt < 4; dt++)
            #pragma unroll
            for (int r = 0; r < 4; r++)
                acc[dt][r] += Cf[wq * 1024 + (dt * 16 + g * 4 + r) * 16 + m16];
        float invl = 1.f / (l + Lf[wq * 16 + m16]);
        unsigned short* Ob = OT + (size_t)bb * 4096 * 256;
        size_t obase = (size_t)(q0 + m16) * 256 + h * 64 + g * 4;
        #pragma unroll
        for (int dt = 0; dt < 4; dt++) {
            unsigned short o4[4];
            #pragma unroll
            for (int r = 0; r < 4; r++) o4[r] = f2bf(acc[dt][r] * invl);
            *(uint2*)&Ob[obase + dt * 16] = *(const uint2*)o4;
        }
    }
}

// ---------------------------------------------------------------- out proj
__global__ __launch_bounds__(256) void outproj(const unsigned short* __restrict__ Ot,
                                               const unsigned short* __restrict__ Wo,
                                               const float* __restrict__ bias,
                                               const float* __restrict__ resid,
                                               float* __restrict__ out) {
    int bb = blockIdx.z;
    int n0 = blockIdx.x * 128;
    int o0 = blockIdx.y * 64;
    int w = threadIdx.x >> 6, lane = threadIdx.x & 63;
    int m16 = lane & 15, g = lane >> 4;
    const unsigned short* Ob = Ot + (size_t)bb * 4096 * 256;
    int orow = o0 + w * 16 + m16;
    f32x4 acc[8] = {};
    #pragma unroll
    for (int k0 = 0; k0 < 256; k0 += 32) {
        short8 a = ld8(Wo + (size_t)orow * 256 + k0 + g * 8);
        #pragma unroll
        for (int ct = 0; ct < 8; ct++) {
            short8 bf = ld8(Ob + (size_t)(n0 + ct * 16 + m16) * 256 + k0 + g * 8);
            acc[ct] = MFMA(a, bf, acc[ct]);
        }
    }
    float biasr[4];
    #pragma unroll
    for (int r = 0; r < 4; r++) biasr[r] = bias[o0 + w * 16 + g * 4 + r];
    #pragma unroll
    for (int ct = 0; ct < 8; ct++)
        #pragma unroll
        for (int r = 0; r < 4; r++) {
            int o = o0 + w * 16 + g * 4 + r;
            int n = n0 + ct * 16 + m16;
            size_t idx = ((size_t)bb * 256 + o) * 4096 + n;
            out[idx] = acc[ct][r] + biasr[r] + resid[idx];
        }
}

// ---------------------------------------------------------------- launch
extern "C" void kernel_launch(void* const* d_in, const int* in_sizes, int n_in,
                              void* d_out, int out_size, void* d_ws, size_t ws_size,
                              hipStream_t stream) {
    const float* input  = (const float*)d_in[0];
    const float* cctx   = (const float*)d_in[1];
    const float* gn_w   = (const float*)d_in[2];
    const float* gn_b   = (const float*)d_in[3];
    const float* wq     = (const float*)d_in[4];
    const float* wkv    = (const float*)d_in[5];
    const float* wout_w = (const float*)d_in[6];
    const float* wout_b = (const float*)d_in[7];
    float* out = (float*)d_out;

    unsigned short* ws = (unsigned short*)d_ws;
    unsigned short* wq_bf   = ws;                   //  65536 ush
    unsigned short* wkv_bf  = ws + 65536;           // 131072
    unsigned short* wout_bf = ws + 196608;          //  65536
    unsigned short* nqT  = ws + 262144;             // 2*4096*256
    unsigned short* nkvT = nqT + 2097152;
    unsigned short* QT   = nkvT + 2097152;
    unsigned short* KF   = QT + 2097152;            // 8 bh * 262144
    unsigned short* VF   = KF + 2097152;
    unsigned short* OtT  = VF + 2097152;            // total ~24.5 MiB

    wcvt<<<1024, 256, 0, stream>>>(wq, wkv, wout_w, ws);
    gnorm<<<128, 256, 0, stream>>>(input, cctx, nqT, nkvT, gn_w, gn_b);
    proj_all<<<dim3(32, 12, 2), 256, 0, stream>>>(nqT, nkvT, wq_bf, wkv_bf, QT, KF, VF);
    attn<<<512, 512, 0, stream>>>(QT, KF, VF, OtT);
    outproj<<<dim3(32, 4, 2), 256, 0, stream>>>(OtT, wout_bf, wout_b, input, out);
}